// Round 10
// baseline (286.248 us; speedup 1.0000x reference)
//
#include <hip/hip_runtime.h>

#define NN   100000
#define NE   1600000
#define NH   4
#define FIN  128
#define FOUT 32
#define HF   128
#define SLOPE 0.2f

#define PBKT  64                    // dst nodes per partition bucket
#define PNB   ((NN+PBKT-1)/PBKT)    // 1563 buckets
#define CAP   2048                  // slots per bucket (mean 1024, sd 32)
#define NMF   1563                  // mfma blocks (64 nodes each)
#define NPART 98                    // partition blocks (16384 edges each)
#define EPB   16384
#define LCSR  768                   // LDS csr capacity per half-bucket
#define NGB   2048                  // persistent gather blocks (8/CU)

typedef __attribute__((ext_vector_type(8))) short short8v;   // 8 bf16 (4 VGPRs)
typedef __attribute__((ext_vector_type(4))) float f32x4;

__device__ __forceinline__ unsigned int bpack(float lo, float hi){
    unsigned int ul = __float_as_uint(lo), uh = __float_as_uint(hi);
    ul = (ul + 0x7fffu + ((ul>>16)&1u)) >> 16;
    uh = (uh + 0x7fffu + ((uh>>16)&1u)) >> 16;
    return ul | (uh<<16);
}
__device__ __forceinline__ short bf16of(float f){
    unsigned int u = __float_as_uint(f);
    return (short)((u + 0x7fffu + ((u>>16)&1u)) >> 16);
}
__device__ __forceinline__ float blo(unsigned int u){ return __uint_as_float(u<<16); }
__device__ __forceinline__ float bhi(unsigned int u){ return __uint_as_float(u&0xffff0000u); }

// ---- kernel 0: one-block prep. bf16 MFMA B-fragments of W and W@a; zero cnt, wctr.
__global__ __launch_bounds__(1024) void prep_k(
    const float* __restrict__ w, const float* __restrict__ a,
    short* __restrict__ wfrag, short* __restrict__ wafrag,
    int* __restrict__ cnt, int* __restrict__ wctr)
{
    __shared__ float wal[1024];            // wa[8][128]
    int t = threadIdx.x;
    if (t == 0) *wctr = 0;
    {
        int s = t>>7, f = t&127, h = s&3;
        const float* ap = a + h*64 + (s>>2)*32;
        const float* wp = w + (size_t)h*4096 + f*32;
        float acc = 0.f;
        #pragma unroll
        for (int o=0;o<32;o++) acc = fmaf(wp[o], ap[o], acc);
        wal[s*128 + f] = acc;
    }
    __syncthreads();
    for (int idx=t; idx<2048; idx+=1024){
        int lane = idx&63, ks=(idx>>6)&3, cf=(idx>>8)&1, wvv=idx>>9;
        int col = wvv*32 + cf*16 + (lane&15);
        int fb  = ks*32 + (lane>>4)*8;
        const float* wp = w + (size_t)(col>>5)*4096 + (col&31);
        short8v bv;
        #pragma unroll
        for (int j=0;j<8;j++) bv[j] = bf16of(wp[(size_t)(fb+j)*32]);
        ((short8v*)wfrag)[idx] = bv;
    }
    if (t < 256){
        int lane = t&63, ks = t>>6;
        int l15 = lane&15, fb = ks*32 + (lane>>4)*8;
        short8v bv;
        #pragma unroll
        for (int j=0;j<8;j++) bv[j] = (l15<8) ? bf16of(wal[l15*128 + fb + j]) : (short)0;
        ((short8v*)wafrag)[t] = bv;
    }
    for (int i=t;i<PNB;i+=1024) cnt[i]=0;
}

// ---- kernel 1: FUSED role-split kernel.
// bid<1568 && bid%16==15 -> partition role (16K edges); else 64-node MFMA h=x@W.
__global__ __launch_bounds__(256) void fused_k(
    const float* __restrict__ x, const short* __restrict__ wfrag,
    const short* __restrict__ wafrag, unsigned int* __restrict__ hb,
    float* __restrict__ asrc, float* __restrict__ adst,
    const int* __restrict__ esrc, const int* __restrict__ edst,
    int* __restrict__ cnt, unsigned int* __restrict__ parr)
{
    __shared__ char smem[16384];          // mfma A-tile 16KB / part hist+bcur 12.5KB
    const int bid = blockIdx.x;
    const int t   = threadIdx.x;
    const bool is_part = (bid < 16*NPART) && ((bid & 15) == 15);

    if (is_part){
        // ---------- partition role: 16384 edges ----------
        int* hist = (int*)smem;
        int* bcur = hist + PNB;
        for (int i=t;i<PNB;i+=256) hist[i]=0;
        __syncthreads();
        int base = (bid >> 4) * EPB;
        #pragma unroll 8
        for (int k=0;k<64;k++){
            int e = base + k*256 + t;
            if (e < NE) atomicAdd(&hist[edst[e]>>6], 1);
        }
        __syncthreads();
        for (int i=t;i<PNB;i+=256)
            bcur[i] = hist[i] ? atomicAdd(&cnt[i], hist[i]) : 0;
        __syncthreads();
        #pragma unroll 8
        for (int k=0;k<64;k++){
            int e = base + k*256 + t;
            if (e < NE){
                int d = edst[e], s = esrc[e];
                int pos = atomicAdd(&bcur[d>>6], 1);
                parr[(size_t)(d>>6)*CAP + pos] = ((unsigned int)s<<6) | (unsigned int)(d & 63);
            }
        }
        return;
    }

    // ---------- mfma role ----------
    const int mi = (bid < 16*NPART) ? (bid - (bid>>4)) : (bid - NPART);
    char* lds = smem;
    const int n0 = mi*64;

    #pragma unroll
    for (int p=0; p<8; ++p){
        int r  = p*8 + (t>>5);
        int cq = t & 31;
        int nr = n0 + r; if (nr > NN-1) nr = NN-1;
        float4 v = *(const float4*)(x + (size_t)nr*FIN + cq*4);
        unsigned int lo = bpack(v.x, v.y), hi = bpack(v.z, v.w);
        int cb = (cq*8) ^ ((r&7)<<4);
        *(uint2*)(lds + r*256 + cb) = make_uint2(lo, hi);
    }
    __syncthreads();

    const int wv   = t>>6;
    const int lane = t&63;
    const int l15  = lane&15;
    const int lk   = (lane>>4)<<3;

    short8v Bf[3][4];
    const short8v* wf  = (const short8v*)wfrag;
    const short8v* waf = (const short8v*)wafrag;
    #pragma unroll
    for (int cf=0; cf<2; ++cf)
        #pragma unroll
        for (int ks=0; ks<4; ++ks)
            Bf[cf][ks] = wf[((wv*2+cf)*4+ks)*64 + lane];
    if (wv==0){
        #pragma unroll
        for (int ks=0; ks<4; ++ks) Bf[2][ks] = waf[ks*64 + lane];
    }

    f32x4 C[4][3];
    #pragma unroll
    for (int rt=0;rt<4;rt++)
        #pragma unroll
        for (int cf=0;cf<3;cf++){ f32x4 z = {0.f,0.f,0.f,0.f}; C[rt][cf] = z; }

    const int axor = (lane&7)<<4;
    #pragma unroll
    for (int rt=0; rt<4; ++rt){
        int row = rt*16 + l15;
        const char* arow = lds + row*256;
        short8v Af[4];
        #pragma unroll
        for (int ks=0; ks<4; ++ks)
            Af[ks] = *(const short8v*)(arow + (((ks<<6) | (lk<<1)) ^ axor));
        #pragma unroll
        for (int ks=0; ks<4; ++ks){
            C[rt][0] = __builtin_amdgcn_mfma_f32_16x16x32_bf16(Af[ks], Bf[0][ks], C[rt][0], 0,0,0);
            C[rt][1] = __builtin_amdgcn_mfma_f32_16x16x32_bf16(Af[ks], Bf[1][ks], C[rt][1], 0,0,0);
            if (wv==0)
                C[rt][2] = __builtin_amdgcn_mfma_f32_16x16x32_bf16(Af[ks], Bf[2][ks], C[rt][2], 0,0,0);
        }
    }

    const int g4 = l15>>2;
    #pragma unroll
    for (int rt=0; rt<4; ++rt){
        #pragma unroll
        for (int cf=0; cf<2; ++cf){
            f32x4 c = C[rt][cf];
            #pragma unroll
            for (int i=0;i<4;i++){
                float v1 = __shfl_xor(c[i], 1);
                float v2 = __shfl_xor(c[i], 2);
                float v3 = __shfl_xor(c[i], 3);
                int node = n0 + rt*16 + ((lane>>4)<<2) + i;
                if ((l15&3)==0 && node < NN){
                    uint2 pk = make_uint2(bpack(c[i], v1), bpack(v2, v3));
                    *(uint2*)(hb + (size_t)node*64 + wv*16 + cf*8 + g4*2) = pk;
                }
            }
        }
    }
    if (wv==0 && l15 < 8){
        #pragma unroll
        for (int rt=0; rt<4; ++rt){
            f32x4 c = C[rt][2];
            #pragma unroll
            for (int i=0;i<4;i++){
                int node = n0 + rt*16 + ((lane>>4)<<2) + i;
                if (node < NN){
                    if (l15 < 4) asrc[(size_t)node*4 + l15]     = c[i];
                    else         adst[(size_t)node*4 + (l15-4)] = c[i];
                }
            }
        }
    }
}

// ---- kernel 2: persistent work-stealing gather over half-buckets ----
__global__ __launch_bounds__(256) void gather_k(
    const int* __restrict__ cnt,
    const unsigned int* __restrict__ parr,
    const float* __restrict__ asrc, const float* __restrict__ adst,
    const unsigned int* __restrict__ hb, const float* __restrict__ bias,
    float* __restrict__ out, int* __restrict__ wctr)
{
    __shared__ int lcount[32], loffs[32], lcur[32], u_s;
    __shared__ int lcsr[LCSR];
    int t = threadIdx.x;
    int wv = t>>6, lane = t&63, head = lane>>4;
    float2 bi = *(const float2*)(bias + 2*lane);
    const unsigned int* hoff = hb + lane;

    for (;;){
        if (t == 0) u_s = atomicAdd(wctr, 1);
        __syncthreads();                 // publishes u_s; also fences prev iteration
        int u = u_s;
        if (u >= PNB*2) break;
        int bkt = u>>1, half = u&1;
        int cb = cnt[bkt]; if (cb > CAP) cb = CAP;
        const unsigned int* pb = parr + (size_t)bkt*CAP;

        if (t < 32) lcount[t] = 0;
        __syncthreads();
        for (int i=t;i<cb;i+=256){
            unsigned int dl = pb[i] & 63u;
            if ((int)(dl>>5) == half) atomicAdd(&lcount[dl&31], 1);
        }
        __syncthreads();
        if (t < 32){
            int v = lcount[t];
            int x = v;
            #pragma unroll
            for (int off=1; off<32; off<<=1){
                int y = __shfl_up(x, off);
                if (t >= off) x += y;
            }
            loffs[t] = x - v;
            lcur[t]  = x - v;
        }
        __syncthreads();
        for (int i=t;i<cb;i+=256){
            unsigned int en = pb[i];
            unsigned int dl = en & 63u;
            if ((int)(dl>>5) == half){
                int pos = atomicAdd(&lcur[dl&31], 1);
                if (pos < LCSR) lcsr[pos] = (int)(en >> 6);
            }
        }
        __syncthreads();

        int dbase = bkt*PBKT + half*32;
        for (int dl = wv; dl < 32; dl += 4){
            int d = dbase + dl;
            if (d >= NN) break;
            int st = loffs[dl];
            int en = st + lcount[dl];
            if (st > LCSR) st = LCSR;
            if (en > LCSR) en = LCSR;

            float ad_h = adst[(size_t)d*NH + head];
            float ssum = 0.f, acc0 = 0.f, acc1 = 0.f;

            int i = st;
            for (; i + 8 <= en; i += 8){
                int s[8]; float av[8]; unsigned int u8[8];
                #pragma unroll
                for (int k=0;k<8;k++) s[k] = lcsr[i+k];
                #pragma unroll
                for (int k=0;k<8;k++) av[k] = asrc[(size_t)s[k]*NH + head];
                #pragma unroll
                for (int k=0;k<8;k++) u8[k] = hoff[(size_t)s[k]*64];
                #pragma unroll
                for (int k=0;k<8;k++){
                    float v = av[k] + ad_h;
                    v = fmaxf(v, SLOPE*v);
                    float p = __expf(v);
                    ssum += p;
                    acc0 = fmaf(p, blo(u8[k]), acc0);
                    acc1 = fmaf(p, bhi(u8[k]), acc1);
                }
            }
            for (; i < en; ++i){
                int s = lcsr[i];
                float av = asrc[(size_t)s*NH + head];
                unsigned int u1 = hoff[(size_t)s*64];
                float v = av + ad_h;
                v = fmaxf(v, SLOPE*v);
                float p = __expf(v);
                ssum += p;
                acc0 = fmaf(p, blo(u1), acc0);
                acc1 = fmaf(p, bhi(u1), acc1);
            }
            float inv = 1.f / (ssum + 1e-16f);
            float2 o = make_float2(acc0*inv + bi.x, acc1*inv + bi.y);
            *(float2*)(out + (size_t)d*HF + 2*lane) = o;
        }
    }
}

extern "C" void kernel_launch(void* const* d_in, const int* in_sizes, int n_in,
                              void* d_out, int out_size, void* d_ws, size_t ws_size,
                              hipStream_t stream)
{
    const float* x    = (const float*)d_in[0];
    const float* w    = (const float*)d_in[1];
    const float* a    = (const float*)d_in[2];
    const float* bias = (const float*)d_in[3];
    const int* esrc   = (const int*)d_in[4];
    const int* edst   = (const int*)d_in[5];
    float* out = (float*)d_out;

    // ws: wfrag s16[16384] | wafrag s16[2048] | hb u32[NN*64] | asrc f32[NN*4]
    //   | adst f32[NN*4] | parr u32[PNB*CAP] | cnt i32[PNB] | wctr i32
    short* wfrag  = (short*)d_ws;
    short* wafrag = wfrag + 16384;
    unsigned int* hb = (unsigned int*)(wafrag + 2048);
    float* as   = (float*)(hb + (size_t)NN*64);
    float* ad   = as + (size_t)NN*NH;
    unsigned int* parr = (unsigned int*)(ad + (size_t)NN*NH);
    int* cnt    = (int*)(parr + (size_t)PNB*CAP);
    int* wctr   = cnt + PNB;

    hipLaunchKernelGGL(prep_k, dim3(1), dim3(1024), 0, stream,
                       w, a, wfrag, wafrag, cnt, wctr);
    hipLaunchKernelGGL(fused_k, dim3(NMF + NPART), dim3(256), 0, stream,
                       x, wfrag, wafrag, hb, as, ad, esrc, edst, cnt, parr);
    hipLaunchKernelGGL(gather_k, dim3(NGB), dim3(256), 0, stream,
                       cnt, parr, as, ad, hb, bias, out, wctr);
}

// Round 11
// 168.408 us; speedup vs baseline: 1.6997x; 1.6997x over previous
//
#include <hip/hip_runtime.h>

#define NN   100000
#define NE   1600000
#define NH   4
#define FIN  128
#define FOUT 32
#define HF   128
#define SLOPE 0.2f

#define PBKT  64                    // dst nodes per partition bucket
#define PNB   ((NN+PBKT-1)/PBKT)    // 1563 buckets
#define CAP   2048                  // slots per bucket (mean 1024, sd 32)
#define NMF   1563                  // mfma blocks (64 nodes each)
#define NPART 391                   // partition blocks (4096 edges each)
#define LCSR  768                   // LDS csr capacity per half-bucket
#define NGB   2048                  // persistent gather blocks (8/CU)

typedef __attribute__((ext_vector_type(8))) short short8v;   // 8 bf16 (4 VGPRs)
typedef __attribute__((ext_vector_type(4))) float f32x4;

__device__ __forceinline__ unsigned int bpack(float lo, float hi){
    unsigned int ul = __float_as_uint(lo), uh = __float_as_uint(hi);
    ul = (ul + 0x7fffu + ((ul>>16)&1u)) >> 16;
    uh = (uh + 0x7fffu + ((uh>>16)&1u)) >> 16;
    return ul | (uh<<16);
}
__device__ __forceinline__ short bf16of(float f){
    unsigned int u = __float_as_uint(f);
    return (short)((u + 0x7fffu + ((u>>16)&1u)) >> 16);
}
__device__ __forceinline__ float blo(unsigned int u){ return __uint_as_float(u<<16); }
__device__ __forceinline__ float bhi(unsigned int u){ return __uint_as_float(u&0xffff0000u); }

// ---- kernel 0: one-block prep. bf16 MFMA B-fragments of W and W@a; zero cnt, wctr.
__global__ __launch_bounds__(1024) void prep_k(
    const float* __restrict__ w, const float* __restrict__ a,
    short* __restrict__ wfrag, short* __restrict__ wafrag,
    int* __restrict__ cnt, int* __restrict__ wctr)
{
    __shared__ float wal[1024];            // wa[8][128]
    int t = threadIdx.x;
    if (t == 0) *wctr = 0;
    {
        int s = t>>7, f = t&127, h = s&3;
        const float* ap = a + h*64 + (s>>2)*32;
        const float* wp = w + (size_t)h*4096 + f*32;
        float acc = 0.f;
        #pragma unroll
        for (int o=0;o<32;o++) acc = fmaf(wp[o], ap[o], acc);
        wal[s*128 + f] = acc;
    }
    __syncthreads();
    for (int idx=t; idx<2048; idx+=1024){
        int lane = idx&63, ks=(idx>>6)&3, cf=(idx>>8)&1, wvv=idx>>9;
        int col = wvv*32 + cf*16 + (lane&15);
        int fb  = ks*32 + (lane>>4)*8;
        const float* wp = w + (size_t)(col>>5)*4096 + (col&31);
        short8v bv;
        #pragma unroll
        for (int j=0;j<8;j++) bv[j] = bf16of(wp[(size_t)(fb+j)*32]);
        ((short8v*)wfrag)[idx] = bv;
    }
    if (t < 256){
        int lane = t&63, ks = t>>6;
        int l15 = lane&15, fb = ks*32 + (lane>>4)*8;
        short8v bv;
        #pragma unroll
        for (int j=0;j<8;j++) bv[j] = (l15<8) ? bf16of(wal[l15*128 + fb + j]) : (short)0;
        ((short8v*)wafrag)[t] = bv;
    }
    for (int i=t;i<PNB;i+=1024) cnt[i]=0;
}

// ---- kernel 1: FUSED role-split kernel (R8 geometry).
// blocks with bid%5==4: edge partition (4096 edges). others: 64-node MFMA h=x@W.
__global__ __launch_bounds__(256) void fused_k(
    const float* __restrict__ x, const short* __restrict__ wfrag,
    const short* __restrict__ wafrag, unsigned int* __restrict__ hb,
    float* __restrict__ asrc, float* __restrict__ adst,
    const int* __restrict__ esrc, const int* __restrict__ edst,
    int* __restrict__ cnt, unsigned int* __restrict__ parr)
{
    __shared__ char smem[16384];          // mfma A-tile 16KB / part hist+bcur 12.5KB
    const int bid = blockIdx.x;
    const int t   = threadIdx.x;
    const int r5  = bid % 5;

    if (r5 == 4){
        // ---------- partition role: 4096 edges ----------
        int* hist = (int*)smem;
        int* bcur = hist + PNB;
        for (int i=t;i<PNB;i+=256) hist[i]=0;
        __syncthreads();
        int base = (bid/5)*4096;
        #pragma unroll
        for (int k=0;k<16;k++){
            int e = base + k*256 + t;
            if (e < NE) atomicAdd(&hist[edst[e]>>6], 1);
        }
        __syncthreads();
        for (int i=t;i<PNB;i+=256)
            bcur[i] = hist[i] ? atomicAdd(&cnt[i], hist[i]) : 0;
        __syncthreads();
        #pragma unroll
        for (int k=0;k<16;k++){
            int e = base + k*256 + t;
            if (e < NE){
                int d = edst[e], s = esrc[e];
                int pos = atomicAdd(&bcur[d>>6], 1);
                parr[(size_t)(d>>6)*CAP + pos] = ((unsigned int)s<<6) | (unsigned int)(d & 63);
            }
        }
        return;
    }

    // ---------- mfma role ----------
    const int mi = (bid/5)*4 + r5;
    if (mi >= NMF) return;
    char* lds = smem;
    const int n0 = mi*64;

    #pragma unroll
    for (int p=0; p<8; ++p){
        int r  = p*8 + (t>>5);
        int cq = t & 31;
        int nr = n0 + r; if (nr > NN-1) nr = NN-1;
        float4 v = *(const float4*)(x + (size_t)nr*FIN + cq*4);
        unsigned int lo = bpack(v.x, v.y), hi = bpack(v.z, v.w);
        int cb = (cq*8) ^ ((r&7)<<4);
        *(uint2*)(lds + r*256 + cb) = make_uint2(lo, hi);
    }
    __syncthreads();

    const int wv   = t>>6;
    const int lane = t&63;
    const int l15  = lane&15;
    const int lk   = (lane>>4)<<3;

    short8v Bf[3][4];
    const short8v* wf  = (const short8v*)wfrag;
    const short8v* waf = (const short8v*)wafrag;
    #pragma unroll
    for (int cf=0; cf<2; ++cf)
        #pragma unroll
        for (int ks=0; ks<4; ++ks)
            Bf[cf][ks] = wf[((wv*2+cf)*4+ks)*64 + lane];
    if (wv==0){
        #pragma unroll
        for (int ks=0; ks<4; ++ks) Bf[2][ks] = waf[ks*64 + lane];
    }

    f32x4 C[4][3];
    #pragma unroll
    for (int rt=0;rt<4;rt++)
        #pragma unroll
        for (int cf=0;cf<3;cf++){ f32x4 z = {0.f,0.f,0.f,0.f}; C[rt][cf] = z; }

    const int axor = (lane&7)<<4;
    #pragma unroll
    for (int rt=0; rt<4; ++rt){
        int row = rt*16 + l15;
        const char* arow = lds + row*256;
        short8v Af[4];
        #pragma unroll
        for (int ks=0; ks<4; ++ks)
            Af[ks] = *(const short8v*)(arow + (((ks<<6) | (lk<<1)) ^ axor));
        #pragma unroll
        for (int ks=0; ks<4; ++ks){
            C[rt][0] = __builtin_amdgcn_mfma_f32_16x16x32_bf16(Af[ks], Bf[0][ks], C[rt][0], 0,0,0);
            C[rt][1] = __builtin_amdgcn_mfma_f32_16x16x32_bf16(Af[ks], Bf[1][ks], C[rt][1], 0,0,0);
            if (wv==0)
                C[rt][2] = __builtin_amdgcn_mfma_f32_16x16x32_bf16(Af[ks], Bf[2][ks], C[rt][2], 0,0,0);
        }
    }

    const int g4 = l15>>2;
    #pragma unroll
    for (int rt=0; rt<4; ++rt){
        #pragma unroll
        for (int cf=0; cf<2; ++cf){
            f32x4 c = C[rt][cf];
            #pragma unroll
            for (int i=0;i<4;i++){
                float v1 = __shfl_xor(c[i], 1);
                float v2 = __shfl_xor(c[i], 2);
                float v3 = __shfl_xor(c[i], 3);
                int node = n0 + rt*16 + ((lane>>4)<<2) + i;
                if ((l15&3)==0 && node < NN){
                    uint2 pk = make_uint2(bpack(c[i], v1), bpack(v2, v3));
                    *(uint2*)(hb + (size_t)node*64 + wv*16 + cf*8 + g4*2) = pk;
                }
            }
        }
    }
    if (wv==0 && l15 < 8){
        #pragma unroll
        for (int rt=0; rt<4; ++rt){
            f32x4 c = C[rt][2];
            #pragma unroll
            for (int i=0;i<4;i++){
                int node = n0 + rt*16 + ((lane>>4)<<2) + i;
                if (node < NN){
                    if (l15 < 4) asrc[(size_t)node*4 + l15]     = c[i];
                    else         adst[(size_t)node*4 + (l15-4)] = c[i];
                }
            }
        }
    }
}

// ---- kernel 2: persistent work-stealing gather over half-buckets ----
__global__ __launch_bounds__(256) void gather_k(
    const int* __restrict__ cnt,
    const unsigned int* __restrict__ parr,
    const float* __restrict__ asrc, const float* __restrict__ adst,
    const unsigned int* __restrict__ hb, const float* __restrict__ bias,
    float* __restrict__ out, int* __restrict__ wctr)
{
    __shared__ int lcount[32], loffs[32], lcur[32], u_s;
    __shared__ int lcsr[LCSR];
    int t = threadIdx.x;
    int wv = t>>6, lane = t&63, head = lane>>4;
    float2 bi = *(const float2*)(bias + 2*lane);
    const unsigned int* hoff = hb + lane;

    for (;;){
        if (t == 0) u_s = atomicAdd(wctr, 1);
        __syncthreads();                 // publishes u_s; also fences prev iteration
        int u = u_s;
        if (u >= PNB*2) break;
        int bkt = u>>1, half = u&1;
        int cb = cnt[bkt]; if (cb > CAP) cb = CAP;
        const unsigned int* pb = parr + (size_t)bkt*CAP;

        if (t < 32) lcount[t] = 0;
        __syncthreads();
        for (int i=t;i<cb;i+=256){
            unsigned int dl = pb[i] & 63u;
            if ((int)(dl>>5) == half) atomicAdd(&lcount[dl&31], 1);
        }
        __syncthreads();
        if (t < 32){
            int v = lcount[t];
            int x = v;
            #pragma unroll
            for (int off=1; off<32; off<<=1){
                int y = __shfl_up(x, off);
                if (t >= off) x += y;
            }
            loffs[t] = x - v;
            lcur[t]  = x - v;
        }
        __syncthreads();
        for (int i=t;i<cb;i+=256){
            unsigned int en = pb[i];
            unsigned int dl = en & 63u;
            if ((int)(dl>>5) == half){
                int pos = atomicAdd(&lcur[dl&31], 1);
                if (pos < LCSR) lcsr[pos] = (int)(en >> 6);
            }
        }
        __syncthreads();

        int dbase = bkt*PBKT + half*32;
        for (int dl = wv; dl < 32; dl += 4){
            int d = dbase + dl;
            if (d >= NN) break;
            int st = loffs[dl];
            int en = st + lcount[dl];
            if (st > LCSR) st = LCSR;
            if (en > LCSR) en = LCSR;

            float ad_h = adst[(size_t)d*NH + head];
            float ssum = 0.f, acc0 = 0.f, acc1 = 0.f;

            int i = st;
            for (; i + 8 <= en; i += 8){
                int s[8]; float av[8]; unsigned int u8[8];
                #pragma unroll
                for (int k=0;k<8;k++) s[k] = lcsr[i+k];
                #pragma unroll
                for (int k=0;k<8;k++) av[k] = asrc[(size_t)s[k]*NH + head];
                #pragma unroll
                for (int k=0;k<8;k++) u8[k] = hoff[(size_t)s[k]*64];
                #pragma unroll
                for (int k=0;k<8;k++){
                    float v = av[k] + ad_h;
                    v = fmaxf(v, SLOPE*v);
                    float p = __expf(v);
                    ssum += p;
                    acc0 = fmaf(p, blo(u8[k]), acc0);
                    acc1 = fmaf(p, bhi(u8[k]), acc1);
                }
            }
            for (; i < en; ++i){
                int s = lcsr[i];
                float av = asrc[(size_t)s*NH + head];
                unsigned int u1 = hoff[(size_t)s*64];
                float v = av + ad_h;
                v = fmaxf(v, SLOPE*v);
                float p = __expf(v);
                ssum += p;
                acc0 = fmaf(p, blo(u1), acc0);
                acc1 = fmaf(p, bhi(u1), acc1);
            }
            float inv = 1.f / (ssum + 1e-16f);
            float2 o = make_float2(acc0*inv + bi.x, acc1*inv + bi.y);
            *(float2*)(out + (size_t)d*HF + 2*lane) = o;
        }
    }
}

extern "C" void kernel_launch(void* const* d_in, const int* in_sizes, int n_in,
                              void* d_out, int out_size, void* d_ws, size_t ws_size,
                              hipStream_t stream)
{
    const float* x    = (const float*)d_in[0];
    const float* w    = (const float*)d_in[1];
    const float* a    = (const float*)d_in[2];
    const float* bias = (const float*)d_in[3];
    const int* esrc   = (const int*)d_in[4];
    const int* edst   = (const int*)d_in[5];
    float* out = (float*)d_out;

    // ws: wfrag s16[16384] | wafrag s16[2048] | hb u32[NN*64] | asrc f32[NN*4]
    //   | adst f32[NN*4] | parr u32[PNB*CAP] | cnt i32[PNB] | wctr i32
    short* wfrag  = (short*)d_ws;
    short* wafrag = wfrag + 16384;
    unsigned int* hb = (unsigned int*)(wafrag + 2048);
    float* as   = (float*)(hb + (size_t)NN*64);
    float* ad   = as + (size_t)NN*NH;
    unsigned int* parr = (unsigned int*)(ad + (size_t)NN*NH);
    int* cnt    = (int*)(parr + (size_t)PNB*CAP);
    int* wctr   = cnt + PNB;

    hipLaunchKernelGGL(prep_k, dim3(1), dim3(1024), 0, stream,
                       w, a, wfrag, wafrag, cnt, wctr);
    hipLaunchKernelGGL(fused_k, dim3(NMF + NPART + 1), dim3(256), 0, stream,
                       x, wfrag, wafrag, hb, as, ad, esrc, edst, cnt, parr);
    hipLaunchKernelGGL(gather_k, dim3(NGB), dim3(256), 0, stream,
                       cnt, parr, as, ad, hb, bias, out, wctr);
}

// Round 12
// 129.519 us; speedup vs baseline: 2.2101x; 1.3003x over previous
//
#include <hip/hip_runtime.h>

#define NN   100000
#define NE   1600000
#define NH   4
#define FIN  128
#define FOUT 32
#define HF   128
#define SLOPE 0.2f

#define PBKT  64                    // dst nodes per partition bucket
#define PNB   ((NN+PBKT-1)/PBKT)    // 1563 buckets
#define CAP   2048                  // slots per bucket (mean 1024, sd 32)
#define NMF   1563                  // mfma blocks (64 nodes each)
#define NPART 391                   // partition blocks (4096 edges each)
#define DSLOT 48                    // lcsr slots per dst (mean 16, +8 sigma)

typedef __attribute__((ext_vector_type(8))) short short8v;   // 8 bf16 (4 VGPRs)
typedef __attribute__((ext_vector_type(4))) float f32x4;

__device__ __forceinline__ unsigned int bpack(float lo, float hi){
    unsigned int ul = __float_as_uint(lo), uh = __float_as_uint(hi);
    ul = (ul + 0x7fffu + ((ul>>16)&1u)) >> 16;
    uh = (uh + 0x7fffu + ((uh>>16)&1u)) >> 16;
    return ul | (uh<<16);
}
__device__ __forceinline__ short bf16of(float f){
    unsigned int u = __float_as_uint(f);
    return (short)((u + 0x7fffu + ((u>>16)&1u)) >> 16);
}
__device__ __forceinline__ float blo(unsigned int u){ return __uint_as_float(u<<16); }
__device__ __forceinline__ float bhi(unsigned int u){ return __uint_as_float(u&0xffff0000u); }

// ---- kernel 0: one-block prep. bf16 MFMA B-fragments of W and W@a; zero cnt.
__global__ __launch_bounds__(1024) void prep_k(
    const float* __restrict__ w, const float* __restrict__ a,
    short* __restrict__ wfrag, short* __restrict__ wafrag,
    int* __restrict__ cnt)
{
    __shared__ float wal[1024];            // wa[8][128]
    int t = threadIdx.x;
    {
        int s = t>>7, f = t&127, h = s&3;
        const float* ap = a + h*64 + (s>>2)*32;
        const float* wp = w + (size_t)h*4096 + f*32;
        float acc = 0.f;
        #pragma unroll
        for (int o=0;o<32;o++) acc = fmaf(wp[o], ap[o], acc);
        wal[s*128 + f] = acc;
    }
    __syncthreads();
    for (int idx=t; idx<2048; idx+=1024){
        int lane = idx&63, ks=(idx>>6)&3, cf=(idx>>8)&1, wvv=idx>>9;
        int col = wvv*32 + cf*16 + (lane&15);
        int fb  = ks*32 + (lane>>4)*8;
        const float* wp = w + (size_t)(col>>5)*4096 + (col&31);
        short8v bv;
        #pragma unroll
        for (int j=0;j<8;j++) bv[j] = bf16of(wp[(size_t)(fb+j)*32]);
        ((short8v*)wfrag)[idx] = bv;
    }
    if (t < 256){
        int lane = t&63, ks = t>>6;
        int l15 = lane&15, fb = ks*32 + (lane>>4)*8;
        short8v bv;
        #pragma unroll
        for (int j=0;j<8;j++) bv[j] = (l15<8) ? bf16of(wal[l15*128 + fb + j]) : (short)0;
        ((short8v*)wafrag)[t] = bv;
    }
    for (int i=t;i<PNB;i+=1024) cnt[i]=0;
}

// ---- kernel 1: FUSED role-split kernel (R8 geometry, unchanged).
__global__ __launch_bounds__(256) void fused_k(
    const float* __restrict__ x, const short* __restrict__ wfrag,
    const short* __restrict__ wafrag, unsigned int* __restrict__ hb,
    float* __restrict__ asrc, float* __restrict__ adst,
    const int* __restrict__ esrc, const int* __restrict__ edst,
    int* __restrict__ cnt, unsigned int* __restrict__ parr)
{
    __shared__ char smem[16384];          // mfma A-tile 16KB / part hist+bcur 12.5KB
    const int bid = blockIdx.x;
    const int t   = threadIdx.x;
    const int r5  = bid % 5;

    if (r5 == 4){
        int* hist = (int*)smem;
        int* bcur = hist + PNB;
        for (int i=t;i<PNB;i+=256) hist[i]=0;
        __syncthreads();
        int base = (bid/5)*4096;
        #pragma unroll
        for (int k=0;k<16;k++){
            int e = base + k*256 + t;
            if (e < NE) atomicAdd(&hist[edst[e]>>6], 1);
        }
        __syncthreads();
        for (int i=t;i<PNB;i+=256)
            bcur[i] = hist[i] ? atomicAdd(&cnt[i], hist[i]) : 0;
        __syncthreads();
        #pragma unroll
        for (int k=0;k<16;k++){
            int e = base + k*256 + t;
            if (e < NE){
                int d = edst[e], s = esrc[e];
                int pos = atomicAdd(&bcur[d>>6], 1);
                parr[(size_t)(d>>6)*CAP + pos] = ((unsigned int)s<<6) | (unsigned int)(d & 63);
            }
        }
        return;
    }

    const int mi = (bid/5)*4 + r5;
    if (mi >= NMF) return;
    char* lds = smem;
    const int n0 = mi*64;

    #pragma unroll
    for (int p=0; p<8; ++p){
        int r  = p*8 + (t>>5);
        int cq = t & 31;
        int nr = n0 + r; if (nr > NN-1) nr = NN-1;
        float4 v = *(const float4*)(x + (size_t)nr*FIN + cq*4);
        unsigned int lo = bpack(v.x, v.y), hi = bpack(v.z, v.w);
        int cb = (cq*8) ^ ((r&7)<<4);
        *(uint2*)(lds + r*256 + cb) = make_uint2(lo, hi);
    }
    __syncthreads();

    const int wv   = t>>6;
    const int lane = t&63;
    const int l15  = lane&15;
    const int lk   = (lane>>4)<<3;

    short8v Bf[3][4];
    const short8v* wf  = (const short8v*)wfrag;
    const short8v* waf = (const short8v*)wafrag;
    #pragma unroll
    for (int cf=0; cf<2; ++cf)
        #pragma unroll
        for (int ks=0; ks<4; ++ks)
            Bf[cf][ks] = wf[((wv*2+cf)*4+ks)*64 + lane];
    if (wv==0){
        #pragma unroll
        for (int ks=0; ks<4; ++ks) Bf[2][ks] = waf[ks*64 + lane];
    }

    f32x4 C[4][3];
    #pragma unroll
    for (int rt=0;rt<4;rt++)
        #pragma unroll
        for (int cf=0;cf<3;cf++){ f32x4 z = {0.f,0.f,0.f,0.f}; C[rt][cf] = z; }

    const int axor = (lane&7)<<4;
    #pragma unroll
    for (int rt=0; rt<4; ++rt){
        int row = rt*16 + l15;
        const char* arow = lds + row*256;
        short8v Af[4];
        #pragma unroll
        for (int ks=0; ks<4; ++ks)
            Af[ks] = *(const short8v*)(arow + (((ks<<6) | (lk<<1)) ^ axor));
        #pragma unroll
        for (int ks=0; ks<4; ++ks){
            C[rt][0] = __builtin_amdgcn_mfma_f32_16x16x32_bf16(Af[ks], Bf[0][ks], C[rt][0], 0,0,0);
            C[rt][1] = __builtin_amdgcn_mfma_f32_16x16x32_bf16(Af[ks], Bf[1][ks], C[rt][1], 0,0,0);
            if (wv==0)
                C[rt][2] = __builtin_amdgcn_mfma_f32_16x16x32_bf16(Af[ks], Bf[2][ks], C[rt][2], 0,0,0);
        }
    }

    const int g4 = l15>>2;
    #pragma unroll
    for (int rt=0; rt<4; ++rt){
        #pragma unroll
        for (int cf=0; cf<2; ++cf){
            f32x4 c = C[rt][cf];
            #pragma unroll
            for (int i=0;i<4;i++){
                float v1 = __shfl_xor(c[i], 1);
                float v2 = __shfl_xor(c[i], 2);
                float v3 = __shfl_xor(c[i], 3);
                int node = n0 + rt*16 + ((lane>>4)<<2) + i;
                if ((l15&3)==0 && node < NN){
                    uint2 pk = make_uint2(bpack(c[i], v1), bpack(v2, v3));
                    *(uint2*)(hb + (size_t)node*64 + wv*16 + cf*8 + g4*2) = pk;
                }
            }
        }
    }
    if (wv==0 && l15 < 8){
        #pragma unroll
        for (int rt=0; rt<4; ++rt){
            f32x4 c = C[rt][2];
            #pragma unroll
            for (int i=0;i<4;i++){
                int node = n0 + rt*16 + ((lane>>4)<<2) + i;
                if (node < NN){
                    if (l15 < 4) asrc[(size_t)node*4 + l15]     = c[i];
                    else         adst[(size_t)node*4 + (l15-4)] = c[i];
                }
            }
        }
    }
}

// ---- kernel 2: one block per bucket; single-pass fixed-slot CSR build,
// then per-dst 2-edge-per-wave math loop (uint2 hb reads, cross-half combine).
__global__ __launch_bounds__(256) void gather_k(
    const int* __restrict__ cnt,
    const unsigned int* __restrict__ parr,
    const float* __restrict__ asrc, const float* __restrict__ adst,
    const unsigned int* __restrict__ hb, const float* __restrict__ bias,
    float* __restrict__ out)
{
    __shared__ int lcur[PBKT];
    __shared__ int lcsr[PBKT*DSLOT];       // 12 KB
    const int bkt = blockIdx.x;
    const int t = threadIdx.x;
    int cb = cnt[bkt]; if (cb > CAP) cb = CAP;
    const unsigned int* pb = parr + (size_t)bkt*CAP;

    if (t < PBKT) lcur[t] = 0;
    __syncthreads();
    // single-pass build: place each edge directly in its dst's slot range
    for (int i=t; i<cb; i+=256){
        unsigned int en = pb[i];
        int dl = (int)(en & 63u);
        int pos = atomicAdd(&lcur[dl], 1);
        if (pos < DSLOT) lcsr[dl*DSLOT + pos] = (int)(en >> 6);
    }
    __syncthreads();

    const int wv   = t>>6;
    const int lane = t&63;
    const int half = lane>>5;          // 0: even slots, 1: odd slots
    const int l31  = lane&31;
    const int head = l31>>3;           // channels 4*l31..+3 belong to head l31>>3
    const float4 bi = *(const float4*)(bias + 4*l31);
    const uint2* hb2 = (const uint2*)hb;   // row = 32 uint2

    for (int dl = wv; dl < PBKT; dl += 4){
        int d = bkt*PBKT + dl;
        if (d >= NN) break;
        int m = lcur[dl]; if (m > DSLOT) m = DSLOT;
        const int base = dl*DSLOT;

        float ad_h = adst[(size_t)d*NH + head];
        float ssum = 0.f, ac0=0.f, ac1=0.f, ac2=0.f, ac3=0.f;

        int k = 0;
        for (; k + 8 <= m; k += 8){
            int s0 = lcsr[base+k  +half], s1 = lcsr[base+k+2+half];
            int s2 = lcsr[base+k+4+half], s3 = lcsr[base+k+6+half];
            float a0=asrc[(size_t)s0*NH+head], a1=asrc[(size_t)s1*NH+head];
            float a2=asrc[(size_t)s2*NH+head], a3=asrc[(size_t)s3*NH+head];
            uint2 u0=hb2[(size_t)s0*32+l31], u1=hb2[(size_t)s1*32+l31];
            uint2 u2=hb2[(size_t)s2*32+l31], u3=hb2[(size_t)s3*32+l31];
            float v0=a0+ad_h; v0=fmaxf(v0,SLOPE*v0); float p0=__expf(v0);
            float v1=a1+ad_h; v1=fmaxf(v1,SLOPE*v1); float p1=__expf(v1);
            float v2=a2+ad_h; v2=fmaxf(v2,SLOPE*v2); float p2=__expf(v2);
            float v3=a3+ad_h; v3=fmaxf(v3,SLOPE*v3); float p3=__expf(v3);
            ssum += (p0+p1)+(p2+p3);
            ac0 = fmaf(p0,blo(u0.x), fmaf(p1,blo(u1.x), fmaf(p2,blo(u2.x), fmaf(p3,blo(u3.x), ac0))));
            ac1 = fmaf(p0,bhi(u0.x), fmaf(p1,bhi(u1.x), fmaf(p2,bhi(u2.x), fmaf(p3,bhi(u3.x), ac1))));
            ac2 = fmaf(p0,blo(u0.y), fmaf(p1,blo(u1.y), fmaf(p2,blo(u2.y), fmaf(p3,blo(u3.y), ac2))));
            ac3 = fmaf(p0,bhi(u0.y), fmaf(p1,bhi(u1.y), fmaf(p2,bhi(u2.y), fmaf(p3,bhi(u3.y), ac3))));
        }
        for (; k + 2 <= m; k += 2){
            int s0 = lcsr[base+k+half];
            float a0 = asrc[(size_t)s0*NH+head];
            uint2 u0 = hb2[(size_t)s0*32+l31];
            float v0=a0+ad_h; v0=fmaxf(v0,SLOPE*v0); float p0=__expf(v0);
            ssum += p0;
            ac0 = fmaf(p0, blo(u0.x), ac0);
            ac1 = fmaf(p0, bhi(u0.x), ac1);
            ac2 = fmaf(p0, blo(u0.y), ac2);
            ac3 = fmaf(p0, bhi(u0.y), ac3);
        }
        if (k < m && half == 0){       // odd tail: half 0 only
            int s0 = lcsr[base+k];
            float a0 = asrc[(size_t)s0*NH+head];
            uint2 u0 = hb2[(size_t)s0*32+l31];
            float v0=a0+ad_h; v0=fmaxf(v0,SLOPE*v0); float p0=__expf(v0);
            ssum += p0;
            ac0 = fmaf(p0, blo(u0.x), ac0);
            ac1 = fmaf(p0, bhi(u0.x), ac1);
            ac2 = fmaf(p0, blo(u0.y), ac2);
            ac3 = fmaf(p0, bhi(u0.y), ac3);
        }
        // combine the two half-wave partial sums
        ac0 += __shfl_xor(ac0, 32); ac1 += __shfl_xor(ac1, 32);
        ac2 += __shfl_xor(ac2, 32); ac3 += __shfl_xor(ac3, 32);
        ssum += __shfl_xor(ssum, 32);
        if (half == 0){
            float inv = 1.f / (ssum + 1e-16f);
            float4 o = make_float4(ac0*inv + bi.x, ac1*inv + bi.y,
                                   ac2*inv + bi.z, ac3*inv + bi.w);
            *(float4*)(out + (size_t)d*HF + 4*l31) = o;
        }
    }
}

extern "C" void kernel_launch(void* const* d_in, const int* in_sizes, int n_in,
                              void* d_out, int out_size, void* d_ws, size_t ws_size,
                              hipStream_t stream)
{
    const float* x    = (const float*)d_in[0];
    const float* w    = (const float*)d_in[1];
    const float* a    = (const float*)d_in[2];
    const float* bias = (const float*)d_in[3];
    const int* esrc   = (const int*)d_in[4];
    const int* edst   = (const int*)d_in[5];
    float* out = (float*)d_out;

    // ws: wfrag s16[16384] | wafrag s16[2048] | hb u32[NN*64] | asrc f32[NN*4]
    //   | adst f32[NN*4] | parr u32[PNB*CAP] | cnt i32[PNB]
    short* wfrag  = (short*)d_ws;
    short* wafrag = wfrag + 16384;
    unsigned int* hb = (unsigned int*)(wafrag + 2048);
    float* as   = (float*)(hb + (size_t)NN*64);
    float* ad   = as + (size_t)NN*NH;
    unsigned int* parr = (unsigned int*)(ad + (size_t)NN*NH);
    int* cnt    = (int*)(parr + (size_t)PNB*CAP);

    hipLaunchKernelGGL(prep_k, dim3(1), dim3(1024), 0, stream,
                       w, a, wfrag, wafrag, cnt);
    hipLaunchKernelGGL(fused_k, dim3(NMF + NPART + 1), dim3(256), 0, stream,
                       x, wfrag, wafrag, hb, as, ad, esrc, edst, cnt, parr);
    hipLaunchKernelGGL(gather_k, dim3(PNB), dim3(256), 0, stream,
                       cnt, parr, as, ad, hb, bias, out);
}

// Round 13
// 128.930 us; speedup vs baseline: 2.2202x; 1.0046x over previous
//
#include <hip/hip_runtime.h>

#define NN   100000
#define NE   1600000
#define NH   4
#define FIN  128
#define FOUT 32
#define HF   128
#define SLOPE 0.2f

#define PBKT  64                    // dst nodes per partition bucket
#define PNB   ((NN+PBKT-1)/PBKT)    // 1563 buckets
#define CAP   2048                  // slots per bucket (mean 1024, sd 32)
#define NMF   1563                  // mfma blocks (64 nodes each)
#define NPART 391                   // partition blocks (4096 edges each)
#define DSLOT 48                    // lcsr slots per dst (mean 16, +8 sigma)

typedef __attribute__((ext_vector_type(8))) short short8v;   // 8 bf16 (4 VGPRs)
typedef __attribute__((ext_vector_type(4))) float f32x4;

__device__ __forceinline__ unsigned int bpack(float lo, float hi){
    unsigned int ul = __float_as_uint(lo), uh = __float_as_uint(hi);
    ul = (ul + 0x7fffu + ((ul>>16)&1u)) >> 16;
    uh = (uh + 0x7fffu + ((uh>>16)&1u)) >> 16;
    return ul | (uh<<16);
}
__device__ __forceinline__ short bf16of(float f){
    unsigned int u = __float_as_uint(f);
    return (short)((u + 0x7fffu + ((u>>16)&1u)) >> 16);
}
__device__ __forceinline__ float blo(unsigned int u){ return __uint_as_float(u<<16); }
__device__ __forceinline__ float bhi(unsigned int u){ return __uint_as_float(u&0xffff0000u); }

// ---- kernel 0: one-block prep. bf16 MFMA B-fragments of W and W@a; zero cnt.
__global__ __launch_bounds__(1024) void prep_k(
    const float* __restrict__ w, const float* __restrict__ a,
    short* __restrict__ wfrag, short* __restrict__ wafrag,
    int* __restrict__ cnt)
{
    __shared__ float wal[1024];            // wa[8][128]
    int t = threadIdx.x;
    {
        int s = t>>7, f = t&127, h = s&3;
        const float* ap = a + h*64 + (s>>2)*32;
        const float* wp = w + (size_t)h*4096 + f*32;
        float acc = 0.f;
        #pragma unroll
        for (int o=0;o<32;o++) acc = fmaf(wp[o], ap[o], acc);
        wal[s*128 + f] = acc;
    }
    __syncthreads();
    for (int idx=t; idx<2048; idx+=1024){
        int lane = idx&63, ks=(idx>>6)&3, cf=(idx>>8)&1, wvv=idx>>9;
        int col = wvv*32 + cf*16 + (lane&15);
        int fb  = ks*32 + (lane>>4)*8;
        const float* wp = w + (size_t)(col>>5)*4096 + (col&31);
        short8v bv;
        #pragma unroll
        for (int j=0;j<8;j++) bv[j] = bf16of(wp[(size_t)(fb+j)*32]);
        ((short8v*)wfrag)[idx] = bv;
    }
    if (t < 256){
        int lane = t&63, ks = t>>6;
        int l15 = lane&15, fb = ks*32 + (lane>>4)*8;
        short8v bv;
        #pragma unroll
        for (int j=0;j<8;j++) bv[j] = (l15<8) ? bf16of(wal[l15*128 + fb + j]) : (short)0;
        ((short8v*)wafrag)[t] = bv;
    }
    for (int i=t;i<PNB;i+=1024) cnt[i]=0;
}

// ---- kernel 1: FUSED role-split kernel (unchanged).
__global__ __launch_bounds__(256) void fused_k(
    const float* __restrict__ x, const short* __restrict__ wfrag,
    const short* __restrict__ wafrag, unsigned int* __restrict__ hb,
    float* __restrict__ asrc, float* __restrict__ adst,
    const int* __restrict__ esrc, const int* __restrict__ edst,
    int* __restrict__ cnt, unsigned int* __restrict__ parr)
{
    __shared__ char smem[16384];          // mfma A-tile 16KB / part hist+bcur 12.5KB
    const int bid = blockIdx.x;
    const int t   = threadIdx.x;
    const int r5  = bid % 5;

    if (r5 == 4){
        int* hist = (int*)smem;
        int* bcur = hist + PNB;
        for (int i=t;i<PNB;i+=256) hist[i]=0;
        __syncthreads();
        int base = (bid/5)*4096;
        #pragma unroll
        for (int k=0;k<16;k++){
            int e = base + k*256 + t;
            if (e < NE) atomicAdd(&hist[edst[e]>>6], 1);
        }
        __syncthreads();
        for (int i=t;i<PNB;i+=256)
            bcur[i] = hist[i] ? atomicAdd(&cnt[i], hist[i]) : 0;
        __syncthreads();
        #pragma unroll
        for (int k=0;k<16;k++){
            int e = base + k*256 + t;
            if (e < NE){
                int d = edst[e], s = esrc[e];
                int pos = atomicAdd(&bcur[d>>6], 1);
                parr[(size_t)(d>>6)*CAP + pos] = ((unsigned int)s<<6) | (unsigned int)(d & 63);
            }
        }
        return;
    }

    const int mi = (bid/5)*4 + r5;
    if (mi >= NMF) return;
    char* lds = smem;
    const int n0 = mi*64;

    #pragma unroll
    for (int p=0; p<8; ++p){
        int r  = p*8 + (t>>5);
        int cq = t & 31;
        int nr = n0 + r; if (nr > NN-1) nr = NN-1;
        float4 v = *(const float4*)(x + (size_t)nr*FIN + cq*4);
        unsigned int lo = bpack(v.x, v.y), hi = bpack(v.z, v.w);
        int cb = (cq*8) ^ ((r&7)<<4);
        *(uint2*)(lds + r*256 + cb) = make_uint2(lo, hi);
    }
    __syncthreads();

    const int wv   = t>>6;
    const int lane = t&63;
    const int l15  = lane&15;
    const int lk   = (lane>>4)<<3;

    short8v Bf[3][4];
    const short8v* wf  = (const short8v*)wfrag;
    const short8v* waf = (const short8v*)wafrag;
    #pragma unroll
    for (int cf=0; cf<2; ++cf)
        #pragma unroll
        for (int ks=0; ks<4; ++ks)
            Bf[cf][ks] = wf[((wv*2+cf)*4+ks)*64 + lane];
    if (wv==0){
        #pragma unroll
        for (int ks=0; ks<4; ++ks) Bf[2][ks] = waf[ks*64 + lane];
    }

    f32x4 C[4][3];
    #pragma unroll
    for (int rt=0;rt<4;rt++)
        #pragma unroll
        for (int cf=0;cf<3;cf++){ f32x4 z = {0.f,0.f,0.f,0.f}; C[rt][cf] = z; }

    const int axor = (lane&7)<<4;
    #pragma unroll
    for (int rt=0; rt<4; ++rt){
        int row = rt*16 + l15;
        const char* arow = lds + row*256;
        short8v Af[4];
        #pragma unroll
        for (int ks=0; ks<4; ++ks)
            Af[ks] = *(const short8v*)(arow + (((ks<<6) | (lk<<1)) ^ axor));
        #pragma unroll
        for (int ks=0; ks<4; ++ks){
            C[rt][0] = __builtin_amdgcn_mfma_f32_16x16x32_bf16(Af[ks], Bf[0][ks], C[rt][0], 0,0,0);
            C[rt][1] = __builtin_amdgcn_mfma_f32_16x16x32_bf16(Af[ks], Bf[1][ks], C[rt][1], 0,0,0);
            if (wv==0)
                C[rt][2] = __builtin_amdgcn_mfma_f32_16x16x32_bf16(Af[ks], Bf[2][ks], C[rt][2], 0,0,0);
        }
    }

    const int g4 = l15>>2;
    #pragma unroll
    for (int rt=0; rt<4; ++rt){
        #pragma unroll
        for (int cf=0; cf<2; ++cf){
            f32x4 c = C[rt][cf];
            #pragma unroll
            for (int i=0;i<4;i++){
                float v1 = __shfl_xor(c[i], 1);
                float v2 = __shfl_xor(c[i], 2);
                float v3 = __shfl_xor(c[i], 3);
                int node = n0 + rt*16 + ((lane>>4)<<2) + i;
                if ((l15&3)==0 && node < NN){
                    uint2 pk = make_uint2(bpack(c[i], v1), bpack(v2, v3));
                    *(uint2*)(hb + (size_t)node*64 + wv*16 + cf*8 + g4*2) = pk;
                }
            }
        }
    }
    if (wv==0 && l15 < 8){
        #pragma unroll
        for (int rt=0; rt<4; ++rt){
            f32x4 c = C[rt][2];
            #pragma unroll
            for (int i=0;i<4;i++){
                int node = n0 + rt*16 + ((lane>>4)<<2) + i;
                if (node < NN){
                    if (l15 < 4) asrc[(size_t)node*4 + l15]     = c[i];
                    else         adst[(size_t)node*4 + (l15-4)] = c[i];
                }
            }
        }
    }
}

// ---- kernel 2: one block per bucket; single-pass fixed-slot CSR build,
// then quarter-wave-per-edge math loop (uint4 hb reads, 8 ch/lane).
__global__ __launch_bounds__(256) void gather_k(
    const int* __restrict__ cnt,
    const unsigned int* __restrict__ parr,
    const float* __restrict__ asrc, const float* __restrict__ adst,
    const unsigned int* __restrict__ hb, const float* __restrict__ bias,
    float* __restrict__ out)
{
    __shared__ int lcur[PBKT];
    __shared__ int lcsr[PBKT*DSLOT];       // 12 KB
    const int bkt = blockIdx.x;
    const int t = threadIdx.x;
    int cb = cnt[bkt]; if (cb > CAP) cb = CAP;
    const unsigned int* pb = parr + (size_t)bkt*CAP;

    if (t < PBKT) lcur[t] = 0;
    __syncthreads();
    for (int i=t; i<cb; i+=256){
        unsigned int en = pb[i];
        int dl = (int)(en & 63u);
        int pos = atomicAdd(&lcur[dl], 1);
        if (pos < DSLOT) lcsr[dl*DSLOT + pos] = (int)(en >> 6);
    }
    __syncthreads();

    const int wv   = t>>6;
    const int lane = t&63;
    const int q    = lane>>4;          // quarter owns edge k+q
    const int l15  = lane&15;          // 8 channels: 8*l15 .. 8*l15+7
    const int head = l15>>2;           // channels 8*l15 fall in head (8*l15)/32
    const uint4* hb4 = (const uint4*)hb;   // row = 16 uint4
    const float4 bi0 = *(const float4*)(bias + 8*l15);
    const float4 bi1 = *(const float4*)(bias + 8*l15 + 4);

    for (int dl = wv; dl < PBKT; dl += 4){
        int d = bkt*PBKT + dl;
        if (d >= NN) break;
        int m = lcur[dl]; if (m > DSLOT) m = DSLOT;
        const int base = dl*DSLOT;

        float ad_h = adst[(size_t)d*NH + head];
        float ssum = 0.f;
        float ac0=0.f, ac1=0.f, ac2=0.f, ac3=0.f, ac4=0.f, ac5=0.f, ac6=0.f, ac7=0.f;

        int k = 0;
        for (; k + 8 <= m; k += 8){
            int sA = lcsr[base+k+q];
            int sB = lcsr[base+k+4+q];
            float aA = asrc[(size_t)sA*NH+head];
            float aB = asrc[(size_t)sB*NH+head];
            uint4 uA = hb4[(size_t)sA*16 + l15];
            uint4 uB = hb4[(size_t)sB*16 + l15];
            float vA=aA+ad_h; vA=fmaxf(vA,SLOPE*vA); float pA=__expf(vA);
            float vB=aB+ad_h; vB=fmaxf(vB,SLOPE*vB); float pB=__expf(vB);
            ssum += pA + pB;
            ac0 = fmaf(pA,blo(uA.x), fmaf(pB,blo(uB.x), ac0));
            ac1 = fmaf(pA,bhi(uA.x), fmaf(pB,bhi(uB.x), ac1));
            ac2 = fmaf(pA,blo(uA.y), fmaf(pB,blo(uB.y), ac2));
            ac3 = fmaf(pA,bhi(uA.y), fmaf(pB,bhi(uB.y), ac3));
            ac4 = fmaf(pA,blo(uA.z), fmaf(pB,blo(uB.z), ac4));
            ac5 = fmaf(pA,bhi(uA.z), fmaf(pB,bhi(uB.z), ac5));
            ac6 = fmaf(pA,blo(uA.w), fmaf(pB,blo(uB.w), ac6));
            ac7 = fmaf(pA,bhi(uA.w), fmaf(pB,bhi(uB.w), ac7));
        }
        for (; k < m; k += 4){
            int r = m - k;
            if (q < r){
                int s = lcsr[base+k+q];
                float a0 = asrc[(size_t)s*NH+head];
                uint4 u = hb4[(size_t)s*16 + l15];
                float v = a0 + ad_h; v = fmaxf(v, SLOPE*v);
                float p = __expf(v);
                ssum += p;
                ac0 = fmaf(p, blo(u.x), ac0);
                ac1 = fmaf(p, bhi(u.x), ac1);
                ac2 = fmaf(p, blo(u.y), ac2);
                ac3 = fmaf(p, bhi(u.y), ac3);
                ac4 = fmaf(p, blo(u.z), ac4);
                ac5 = fmaf(p, bhi(u.z), ac5);
                ac6 = fmaf(p, blo(u.w), ac6);
                ac7 = fmaf(p, bhi(u.w), ac7);
            }
        }
        // combine the four quarter partial sums (same l15 => same channels/head)
        ssum += __shfl_xor(ssum, 16); ssum += __shfl_xor(ssum, 32);
        ac0 += __shfl_xor(ac0, 16); ac0 += __shfl_xor(ac0, 32);
        ac1 += __shfl_xor(ac1, 16); ac1 += __shfl_xor(ac1, 32);
        ac2 += __shfl_xor(ac2, 16); ac2 += __shfl_xor(ac2, 32);
        ac3 += __shfl_xor(ac3, 16); ac3 += __shfl_xor(ac3, 32);
        ac4 += __shfl_xor(ac4, 16); ac4 += __shfl_xor(ac4, 32);
        ac5 += __shfl_xor(ac5, 16); ac5 += __shfl_xor(ac5, 32);
        ac6 += __shfl_xor(ac6, 16); ac6 += __shfl_xor(ac6, 32);
        ac7 += __shfl_xor(ac7, 16); ac7 += __shfl_xor(ac7, 32);
        if (q == 0){
            float inv = 1.f / (ssum + 1e-16f);
            float4 o0 = make_float4(ac0*inv + bi0.x, ac1*inv + bi0.y,
                                    ac2*inv + bi0.z, ac3*inv + bi0.w);
            float4 o1 = make_float4(ac4*inv + bi1.x, ac5*inv + bi1.y,
                                    ac6*inv + bi1.z, ac7*inv + bi1.w);
            float* op = out + (size_t)d*HF + 8*l15;
            *(float4*)op     = o0;
            *(float4*)(op+4) = o1;
        }
    }
}

extern "C" void kernel_launch(void* const* d_in, const int* in_sizes, int n_in,
                              void* d_out, int out_size, void* d_ws, size_t ws_size,
                              hipStream_t stream)
{
    const float* x    = (const float*)d_in[0];
    const float* w    = (const float*)d_in[1];
    const float* a    = (const float*)d_in[2];
    const float* bias = (const float*)d_in[3];
    const int* esrc   = (const int*)d_in[4];
    const int* edst   = (const int*)d_in[5];
    float* out = (float*)d_out;

    // ws: wfrag s16[16384] | wafrag s16[2048] | hb u32[NN*64] | asrc f32[NN*4]
    //   | adst f32[NN*4] | parr u32[PNB*CAP] | cnt i32[PNB]
    short* wfrag  = (short*)d_ws;
    short* wafrag = wfrag + 16384;
    unsigned int* hb = (unsigned int*)(wafrag + 2048);
    float* as   = (float*)(hb + (size_t)NN*64);
    float* ad   = as + (size_t)NN*NH;
    unsigned int* parr = (unsigned int*)(ad + (size_t)NN*NH);
    int* cnt    = (int*)(parr + (size_t)PNB*CAP);

    hipLaunchKernelGGL(prep_k, dim3(1), dim3(1024), 0, stream,
                       w, a, wfrag, wafrag, cnt);
    hipLaunchKernelGGL(fused_k, dim3(NMF + NPART + 1), dim3(256), 0, stream,
                       x, wfrag, wafrag, hb, as, ad, esrc, edst, cnt, parr);
    hipLaunchKernelGGL(gather_k, dim3(PNB), dim3(256), 0, stream,
                       cnt, parr, as, ad, hb, bias, out);
}